// Round 4
// baseline (227.750 us; speedup 1.0000x reference)
//
#include <hip/hip_runtime.h>

// SGE-style gate: B=64, C=512, HW=784, G=8, cpg=64.
//
// R7 = R6 with compile fix: __builtin_nontemporal_store needs a NATIVE
// vector type, not HIP's float4 class -> store via ext_vector_type alias.
//
// R6 rationale: 3-kernel pipeline. R4 (register-resident, minimal traffic) =
// 66us @ 2.37 TB/s (phase-locked 2 blocks/CU, HBM idles during reduce).
// R5 (3-pass single kernel) = 81us @ 3.2 TB/s but 259MB traffic (out-writes
// evict x from LLC; each extra pass = +50MB HBM). Fix both:
// (1) each heavy phase = own barrier-free kernel, thousands of independent
// blocks -> no phase locking, deep MLP; (2) K2/K3 re-read x while LLC-hot;
// (3) K3 nt-stores for out so the 103MB write stream doesn't evict x.
//
//   K1: per-channel mean. 1 wave per row (32768 rows), linear 1KB loads.
//   K2: per-(b,g) gate. column dot over 64 channels (LLC-hot), mu/var,
//       sigmoid -> gate[512][784] in workspace (1.6MB).
//   K3: out = x * gate. grid-stride elementwise, nt-stores.
//
// Workspace layout: gate @ 0 (1,605,632 B), means @ 1,605,632 (131,072 B).

#define HW    784
#define HW4   196
#define CPG   64
#define NG    8
#define NROWS (64 * 512)            // 32768 channel-rows
#define TOT4  (NROWS * HW4)         // 6,422,528 float4 elements

typedef float f32x4 __attribute__((ext_vector_type(4)));

// ---------------- K1: per-channel spatial mean --------------------------
__global__ __launch_bounds__(256)
void k_means(const float* __restrict__ x, float* __restrict__ means) {
    const int t    = threadIdx.x;
    const int lane = t & 63;
    const int row  = blockIdx.x * 4 + (t >> 6);   // global wave id = row
    const float4* xp = (const float4*)x + (size_t)row * HW4;

    const float4 v0 = xp[lane];
    const float4 v1 = xp[lane + 64];
    const float4 v2 = xp[lane + 128];
    float s = ((v0.x + v0.y) + (v0.z + v0.w))
            + ((v1.x + v1.y) + (v1.z + v1.w))
            + ((v2.x + v2.y) + (v2.z + v2.w));
    if (lane < 4) {
        const float4 v3 = xp[192 + lane];
        s += (v3.x + v3.y) + (v3.z + v3.w);
    }
#pragma unroll
    for (int m = 1; m < 64; m <<= 1) s += __shfl_xor(s, m, 64);
    if (lane == 0) means[row] = s * (1.0f / (float)HW);
}

// ---------------- K2: s -> mu/var -> gate -------------------------------
__global__ __launch_bounds__(256)
void k_gate(const float* __restrict__ x, const float* __restrict__ means,
            const float* __restrict__ weight, const float* __restrict__ bias,
            float* __restrict__ gate) {
    __shared__ float mloc[CPG];
    __shared__ float red[8];

    const int t    = threadIdx.x;      // 0..255
    const int lane = t & 63;
    const int wave = t >> 6;           // 0..3
    const int bg   = blockIdx.x;       // b*8 + g
    const int g    = bg & (NG - 1);

    if (t < CPG) mloc[t] = means[bg * CPG + t];
    __syncthreads();

    // thread owns positions p = t, t+256, t+512 (all <784) and t+768 (t<16)
    const float* xs = x + (size_t)bg * (CPG * HW);
    float s0 = 0.f, s1 = 0.f, s2 = 0.f, s3 = 0.f;
#pragma unroll 8
    for (int c = 0; c < CPG; ++c) {
        const float  mc = mloc[c];
        const float* rp = xs + c * HW;
        s0 += rp[t]       * mc;
        s1 += rp[t + 256] * mc;
        s2 += rp[t + 512] * mc;
        if (t < 16) s3 += rp[t + 768] * mc;
    }

    float rs  = s0 + s1 + s2 + s3;
    float rs2 = s0 * s0 + s1 * s1 + s2 * s2 + s3 * s3;
#pragma unroll
    for (int m = 1; m < 64; m <<= 1) {
        rs  += __shfl_xor(rs,  m, 64);
        rs2 += __shfl_xor(rs2, m, 64);
    }
    if (lane == 0) { red[wave] = rs; red[4 + wave] = rs2; }
    __syncthreads();

    const float sum_s  = red[0] + red[1] + red[2] + red[3];
    const float sum_s2 = red[4] + red[5] + red[6] + red[7];
    const float mu   = sum_s * (1.0f / (float)HW);
    const float var  = sum_s2 * (1.0f / (float)HW) - mu * mu;
    const float rstd = rsqrtf(var + 1e-5f);
    const float wg   = weight[g];
    const float bgv  = bias[g];

    float* gr = gate + (size_t)bg * HW;
    {
        const float z0 = (s0 - mu) * rstd * wg + bgv;
        const float z1 = (s1 - mu) * rstd * wg + bgv;
        const float z2 = (s2 - mu) * rstd * wg + bgv;
        gr[t]       = 1.0f / (1.0f + __expf(-z0));
        gr[t + 256] = 1.0f / (1.0f + __expf(-z1));
        gr[t + 512] = 1.0f / (1.0f + __expf(-z2));
        if (t < 16) {
            const float z3 = (s3 - mu) * rstd * wg + bgv;
            gr[t + 768] = 1.0f / (1.0f + __expf(-z3));
        }
    }
}

// ---------------- K3: out = x * gate (nt stores) ------------------------
__global__ __launch_bounds__(256)
void k_mul(const float* __restrict__ x, const float* __restrict__ gate,
           float* __restrict__ out) {
    const int tid    = blockIdx.x * 256 + threadIdx.x;
    const int stride = gridDim.x * 256;
    const float4* x4 = (const float4*)x;
    const float4* g4 = (const float4*)gate;
    f32x4*        o4 = (f32x4*)out;

    for (int i = tid; i < TOT4; i += stride) {
        const int row = i / HW4;          // channel-row (bg*64 + c)
        const int h4  = i - row * HW4;    // float4 index within row
        const int bg  = row >> 6;
        const float4 v  = x4[i];
        const float4 gv = g4[bg * HW4 + h4];
        f32x4 o;
        o.x = v.x * gv.x; o.y = v.y * gv.y;
        o.z = v.z * gv.z; o.w = v.w * gv.w;
        __builtin_nontemporal_store(o, &o4[i]);
    }
}

extern "C" void kernel_launch(void* const* d_in, const int* in_sizes, int n_in,
                              void* d_out, int out_size, void* d_ws, size_t ws_size,
                              hipStream_t stream) {
    const float* x      = (const float*)d_in[0];
    const float* weight = (const float*)d_in[1];
    const float* bias   = (const float*)d_in[2];
    float* out   = (float*)d_out;
    float* gate  = (float*)d_ws;                         // 512*784*4 = 1,605,632 B
    float* means = (float*)((char*)d_ws + 1605632);      // 32768*4   =   131,072 B

    k_means<<<dim3(NROWS / 4), dim3(256), 0, stream>>>(x, means);
    k_gate <<<dim3(512),       dim3(256), 0, stream>>>(x, means, weight, bias, gate);
    k_mul  <<<dim3(4096),      dim3(256), 0, stream>>>(x, gate, out);
}

// Round 5
// 213.117 us; speedup vs baseline: 1.0687x; 1.0687x over previous
//
#include <hip/hip_runtime.h>

// SGE-style gate: B=64, C=512, HW=784, G=8, cpg=64. One block per (b,g).
//
// R8: fused single-pass with LDS-staged tile in 8 double-buffered eighths.
// Evidence: R0/R4 register-resident = 66us (AGPR parking throttles load
// stream, 1 block/CU); R5/R7 multi-pass = 3.2TB/s streams but 1.5-3x traffic
// (net worse); fillBuffer calibration = 6.8TB/s achievable. This keeps
// minimal traffic (1 HBM read + L2/LLC-warm re-read + 1 HBM write) AND a
// deep load pipeline: each eighth (8 rows, 25KB) is reg-loaded (prefetched
// one ahead), ds_written, row-meaned (1 wave/row), and column-accumulated
// into per-thread s registers. 25KB/block in flight >> 9.2KB Little's-law
// need; no register residency of the tile -> no AGPR trap.
// LDS 53.4KB, 512 thr, bounds(512,4) -> 2 blocks/CU, all 512 blocks
// co-resident; cross-block overlap covers barrier/reduce gaps.
// Epilogue: re-read x (L2/LLC-warm), nt-store out (don't evict x from LLC).

#define HW     784
#define HW4    196          // float4 per channel-row
#define NG     8
#define TILE4  12544        // 64 * 196 float4 per (b,g) tile
#define EF4    1568         // float4 per eighth (8 rows)
#define NE     8

typedef float f32x4 __attribute__((ext_vector_type(4)));

__global__ __launch_bounds__(512, 4)
void sge_kernel(const float* __restrict__ x,
                const float* __restrict__ weight,
                const float* __restrict__ bias,
                float* __restrict__ out) {
    __shared__ float stage[2][8 * HW];   // double-buffered eighth: 2 x 25,088 B
    __shared__ float gbuf[HW];
    __shared__ float smean[8];
    __shared__ float red[16];

    const int t    = threadIdx.x;        // 0..511
    const int lane = t & 63;
    const int wave = t >> 6;             // 0..7
    const int bg   = blockIdx.x;
    const int g    = bg & (NG - 1);

    const float4* xt = (const float4*)x + (size_t)bg * TILE4;

    // chunk map per eighth: c = t, t+512, t+1024, (t<32: t+1536)  (1568 total)
    const bool x3   = (t < (EF4 - 3 * 512));   // t < 32
    const bool has1 = (t < (HW - 512));        // t < 272

    float4 a0, a1, a2, a3, b0, b1, b2, b3;
    float acc0 = 0.f, acc1 = 0.f;

    // prologue: eighth 0 -> reg set A
    a0 = xt[t]; a1 = xt[t + 512]; a2 = xt[t + 1024];
    if (x3) a3 = xt[t + 1536];

    for (int e = 0; e < NE; ++e) {
        float4* sh = (float4*)stage[e & 1];
        if ((e & 1) == 0) {
            sh[t] = a0; sh[t + 512] = a1; sh[t + 1024] = a2;
            if (x3) sh[t + 1536] = a3;
            if (e + 1 < NE) {                       // prefetch next eighth
                const float4* src = xt + (e + 1) * EF4;
                b0 = src[t]; b1 = src[t + 512]; b2 = src[t + 1024];
                if (x3) b3 = src[t + 1536];
            }
        } else {
            sh[t] = b0; sh[t + 512] = b1; sh[t + 1024] = b2;
            if (x3) sh[t + 1536] = b3;
            if (e + 1 < NE) {
                const float4* src = xt + (e + 1) * EF4;
                a0 = src[t]; a1 = src[t + 512]; a2 = src[t + 1024];
                if (x3) a3 = src[t + 1536];
            }
        }
        __syncthreads();

        // per-channel means of the 8 staged rows: wave w sums row w
        {
            const float4* row4 = (const float4*)(stage[e & 1] + wave * HW);
            const float4 v0 = row4[lane];
            const float4 v1 = row4[lane + 64];
            const float4 v2 = row4[lane + 128];
            float s = ((v0.x + v0.y) + (v0.z + v0.w))
                    + ((v1.x + v1.y) + (v1.z + v1.w))
                    + ((v2.x + v2.y) + (v2.z + v2.w));
            if (lane < 4) {
                const float4 v3 = row4[lane + 192];
                s += (v3.x + v3.y) + (v3.z + v3.w);
            }
#pragma unroll
            for (int m = 1; m < 64; m <<= 1) s += __shfl_xor(s, m, 64);
            if (lane == 0) smean[wave] = s * (1.0f / (float)HW);
        }
        __syncthreads();

        // weighted column accumulate into per-thread s registers
        {
            const float* sb = stage[e & 1];
            const float m0 = smean[0], m1 = smean[1], m2 = smean[2], m3 = smean[3];
            const float m4 = smean[4], m5 = smean[5], m6 = smean[6], m7 = smean[7];
            acc0 += sb[t]          * m0 + sb[t + HW]     * m1
                  + sb[t + 2 * HW] * m2 + sb[t + 3 * HW] * m3
                  + sb[t + 4 * HW] * m4 + sb[t + 5 * HW] * m5
                  + sb[t + 6 * HW] * m6 + sb[t + 7 * HW] * m7;
            if (has1) {
                const int p = t + 512;
                acc1 += sb[p]          * m0 + sb[p + HW]     * m1
                      + sb[p + 2 * HW] * m2 + sb[p + 3 * HW] * m3
                      + sb[p + 4 * HW] * m4 + sb[p + 5 * HW] * m5
                      + sb[p + 6 * HW] * m6 + sb[p + 7 * HW] * m7;
            }
        }
        // no barrier: next iteration ds_writes the OTHER half; its first
        // barrier orders the reuse (last readers of that half finished
        // before this iteration's first barrier).
    }

    // ---- block reduction for mu, var (784 s-values) ----
    float rs  = acc0 + (has1 ? acc1 : 0.f);
    float rs2 = acc0 * acc0 + (has1 ? acc1 * acc1 : 0.f);
#pragma unroll
    for (int m = 1; m < 64; m <<= 1) {
        rs  += __shfl_xor(rs,  m, 64);
        rs2 += __shfl_xor(rs2, m, 64);
    }
    if (lane == 0) { red[wave] = rs; red[8 + wave] = rs2; }
    __syncthreads();

    float sum_s = 0.f, sum_s2 = 0.f;
#pragma unroll
    for (int w = 0; w < 8; ++w) { sum_s += red[w]; sum_s2 += red[8 + w]; }
    const float mu   = sum_s * (1.0f / (float)HW);
    const float var  = sum_s2 * (1.0f / (float)HW) - mu * mu;
    const float rstd = rsqrtf(var + 1e-5f);
    const float wg   = weight[g];
    const float bv   = bias[g];

    {
        const float z0 = (acc0 - mu) * rstd * wg + bv;
        gbuf[t] = 1.0f / (1.0f + __expf(-z0));
        if (has1) {
            const float z1 = (acc1 - mu) * rstd * wg + bv;
            gbuf[t + 512] = 1.0f / (1.0f + __expf(-z1));
        }
    }
    __syncthreads();

    // ---- epilogue: re-read x (L2/LLC-warm), out = x * gate, nt-store ----
    const f32x4* x4  = (const f32x4*)x + (size_t)bg * TILE4;
    f32x4*       o4  = (f32x4*)out + (size_t)bg * TILE4;
    const f32x4* gb4 = (const f32x4*)gbuf;

    int q = t % HW4;                      // f4-column of idx = t
#pragma unroll
    for (int r = 0; r < 24; ++r) {
        const int idx = t + r * 512;
        const f32x4 v  = x4[idx];
        const f32x4 gv = gb4[q];
        const f32x4 o  = v * gv;
        __builtin_nontemporal_store(o, &o4[idx]);
        q += 120; if (q >= HW4) q -= HW4;   // (512 mod 196) = 120
    }
    if (t < 256) {                          // tail: 12544 - 24*512 = 256
        const int idx = 12288 + t;
        const f32x4 v = x4[idx];
        const f32x4 o = v * gb4[idx % HW4];
        __builtin_nontemporal_store(o, &o4[idx]);
    }
}

extern "C" void kernel_launch(void* const* d_in, const int* in_sizes, int n_in,
                              void* d_out, int out_size, void* d_ws, size_t ws_size,
                              hipStream_t stream) {
    const float* x      = (const float*)d_in[0];
    const float* weight = (const float*)d_in[1];
    const float* bias   = (const float*)d_in[2];
    float* out = (float*)d_out;
    sge_kernel<<<dim3(512), dim3(512), 0, stream>>>(x, weight, bias, out);
}

// Round 6
// 190.639 us; speedup vs baseline: 1.1947x; 1.1179x over previous
//
#include <hip/hip_runtime.h>

// SGE-style gate: B=64, C=512, HW=784, G=8, cpg=64. One block per (b,g).
//
// R9: read x ONCE via global_load_lds DMA chunks (fire-and-forget, counted
// vmcnt, raw barriers), park the tile in LDS as fp16 (100KB) so the epilogue
// re-reads NOTHING from global. Evidence: R4 reg-resident = 66us (AGPR-parked
// loads, 2.4TB/s MLP cap); R5/R8 re-read x = +66..100MB HBM (LLC can't hold
// it under the write stream); fillBuffer = 6.8TB/s (fire-and-forget wins).
// global_load_lds needs no VGPRs and no occupancy: 2 chunks (49KB) in flight
// per CU >> 9KB Little's-law need.
//
// Per chunk (8 rows, 25088B, double-buffered):
//   [vmcnt(counted) + s_barrier]  chunk e resident (NEVER vmcnt(0) mid-loop)
//   means: wave w reduces row w (fp32, exact)
//   [lgkmcnt(0) + s_barrier]
//   s-accum (fp32, exact) + convert chunk -> xh fp16 (LDS)
//   [lgkmcnt(0) + s_barrier]; issue chunk e+2 into freed buffer
// Then mu/var/gate (fp32), epilogue: out = fp16(x)*gate, plain stores
// (nt-stores dropped: R8 showed +43MB write amplification with nt).
// Precision: only epilogue x is fp16-rounded: err <= |x|*2^-11 ~ 2.7e-3.
//
// LDS: xh 100352 + stage 2x25088 + gate 3136 + smean 32 + red 64 = 153760B
// -> 1 block/CU, dynamic LDS (>64KB static limit), FuncSetAttribute opt-in.

#define HW      784
#define NG      8
#define TILE_F  50176        // floats per (b,g) tile
#define TILE4   12544        // float4 per tile
#define CHUNK_F 6272         // floats per chunk (8 rows)
#define NCH     8

typedef float    f32x4 __attribute__((ext_vector_type(4)));
typedef _Float16 f16x4 __attribute__((ext_vector_type(4)));

#define XH_OFF    0
#define ST_OFF    100352
#define GB_OFF    150528
#define SM_OFF    153664
#define RED_OFF   153696
#define LDS_TOTAL 153760

__device__ __forceinline__ void gload16(const float* g, float* l) {
    __builtin_amdgcn_global_load_lds(
        (const __attribute__((address_space(1))) void*)g,
        (__attribute__((address_space(3))) void*)l, 16, 0, 0);
}

#define WAIT_VM(N)  asm volatile("s_waitcnt vmcnt(" #N ")" ::: "memory")
#define WAIT_LGKM() asm volatile("s_waitcnt lgkmcnt(0)" ::: "memory")
#define RAW_BAR()   do { __builtin_amdgcn_s_barrier(); \
                         __builtin_amdgcn_sched_barrier(0); } while (0)

__global__ __launch_bounds__(512, 1)
void sge_kernel(const float* __restrict__ x, const float* __restrict__ weight,
                const float* __restrict__ bias, float* __restrict__ out) {
    extern __shared__ char smem[];
    _Float16* xh   = (_Float16*)(smem + XH_OFF);   // tile as fp16 [64][784]
    float*    stg  = (float*)(smem + ST_OFF);      // [2][6272] fp32 stage
    float*    gbuf = (float*)(smem + GB_OFF);      // gate[784]
    float*    smean= (float*)(smem + SM_OFF);      // 8 chunk means
    float*    red  = (float*)(smem + RED_OFF);     // 16 reduce slots

    const int t = threadIdx.x, lane = t & 63, wave = t >> 6;   // 512 thr, 8 waves
    const int bg = blockIdx.x, g = bg & (NG - 1);
    const float* xt = x + (size_t)bg * TILE_F;
    const bool has1 = t < (HW - 512);              // t < 272

    // issue chunk e into stage buffer b. Per wave: 3x 1KB DMA (uniform LDS
    // base, HW adds lane*16); wave0 adds the 512B tail (lanes 0-31).
    auto issue = [&](int e, int b) {
        const float* gs = xt + e * CHUNK_F;
        float* ld = stg + b * CHUNK_F;
        const int uo = wave * 768;                 // wave's float offset
        gload16(gs + uo       + lane * 4, ld + uo);
        gload16(gs + uo + 256 + lane * 4, ld + uo + 256);
        gload16(gs + uo + 512 + lane * 4, ld + uo + 512);
        if (wave == 0 && lane < 32)
            gload16(gs + 6144 + lane * 4, ld + 6144);
    };

    issue(0, 0);
    issue(1, 1);

    float acc0 = 0.f, acc1 = 0.f;

    for (int e = 0; e < NCH; ++e) {
        const int b = e & 1;
        // chunk e resident when only chunk e+1's DMAs remain outstanding
        if (e < NCH - 1) { if (wave == 0) WAIT_VM(4); else WAIT_VM(3); }
        else             { WAIT_VM(0); }
        RAW_BAR();

        // ---- per-channel means: wave w reduces row w of the chunk ----
        {
            const f32x4* r4 = (const f32x4*)(stg + b * CHUNK_F + wave * HW);
            const f32x4 v0 = r4[lane], v1 = r4[lane + 64], v2 = r4[lane + 128];
            float s = ((v0.x + v0.y) + (v0.z + v0.w))
                    + ((v1.x + v1.y) + (v1.z + v1.w))
                    + ((v2.x + v2.y) + (v2.z + v2.w));
            if (lane < 4) {
                const f32x4 v3 = r4[lane + 192];
                s += (v3.x + v3.y) + (v3.z + v3.w);
            }
#pragma unroll
            for (int m = 1; m < 64; m <<= 1) s += __shfl_xor(s, m, 64);
            if (lane == 0) smean[wave] = s * (1.0f / (float)HW);
        }
        WAIT_LGKM(); RAW_BAR();            // smean visible to all waves

        // ---- s-accumulate (fp32) + convert chunk to fp16 into xh ----
        {
            const float* sb = stg + b * CHUNK_F;
            const float m0 = smean[0], m1 = smean[1], m2 = smean[2], m3 = smean[3];
            const float m4 = smean[4], m5 = smean[5], m6 = smean[6], m7 = smean[7];
            acc0 += sb[t]          * m0 + sb[t + HW]     * m1
                  + sb[t + 2 * HW] * m2 + sb[t + 3 * HW] * m3
                  + sb[t + 4 * HW] * m4 + sb[t + 5 * HW] * m5
                  + sb[t + 6 * HW] * m6 + sb[t + 7 * HW] * m7;
            if (has1) {
                const int p = t + 512;
                acc1 += sb[p]          * m0 + sb[p + HW]     * m1
                      + sb[p + 2 * HW] * m2 + sb[p + 3 * HW] * m3
                      + sb[p + 4 * HW] * m4 + sb[p + 5 * HW] * m5
                      + sb[p + 6 * HW] * m6 + sb[p + 7 * HW] * m7;
            }
            const f32x4* s4 = (const f32x4*)sb;
            f16x4* x4h = (f16x4*)xh + e * 1568;
            x4h[t]        = __builtin_convertvector(s4[t],        f16x4);
            x4h[t + 512]  = __builtin_convertvector(s4[t + 512],  f16x4);
            x4h[t + 1024] = __builtin_convertvector(s4[t + 1024], f16x4);
            if (t < 32)
                x4h[t + 1536] = __builtin_convertvector(s4[t + 1536], f16x4);
        }
        WAIT_LGKM(); RAW_BAR();            // stage[b] free; xh writes drained
        if (e + 2 < NCH) issue(e + 2, b);  // refill freed buffer
    }

    // ---- mu/var over the 784 s-values ----
    float rs  = acc0 + (has1 ? acc1 : 0.f);
    float rs2 = acc0 * acc0 + (has1 ? acc1 * acc1 : 0.f);
#pragma unroll
    for (int m = 1; m < 64; m <<= 1) {
        rs  += __shfl_xor(rs,  m, 64);
        rs2 += __shfl_xor(rs2, m, 64);
    }
    if (lane == 0) { red[wave] = rs; red[8 + wave] = rs2; }
    __syncthreads();                       // vmcnt already 0 here
    float ss = 0.f, ss2 = 0.f;
#pragma unroll
    for (int w = 0; w < 8; ++w) { ss += red[w]; ss2 += red[8 + w]; }
    const float mu   = ss * (1.0f / (float)HW);
    const float var  = ss2 * (1.0f / (float)HW) - mu * mu;
    const float rstd = rsqrtf(var + 1e-5f);
    const float wg   = weight[g];
    const float bv   = bias[g];

    gbuf[t] = 1.0f / (1.0f + __expf(-((acc0 - mu) * rstd * wg + bv)));
    if (has1)
        gbuf[t + 512] = 1.0f / (1.0f + __expf(-((acc1 - mu) * rstd * wg + bv)));
    __syncthreads();

    // ---- epilogue: out = fp16(x) * gate, straight from LDS, plain stores ----
    const f16x4* x4h = (const f16x4*)xh;
    const f32x4* gb4 = (const f32x4*)gbuf;
    f32x4* o4 = (f32x4*)(out + (size_t)bg * TILE_F);
    int col = t % 196;
#pragma unroll
    for (int r = 0; r < 24; ++r) {
        const int idx = t + r * 512;
        const f32x4 xv = __builtin_convertvector(x4h[idx], f32x4);
        o4[idx] = xv * gb4[col];
        col += 120; if (col >= 196) col -= 196;   // 512 mod 196
    }
    if (t < 256) {
        const int idx = 12288 + t;
        const f32x4 xv = __builtin_convertvector(x4h[idx], f32x4);
        o4[idx] = xv * gb4[idx % 196];
    }
}

extern "C" void kernel_launch(void* const* d_in, const int* in_sizes, int n_in,
                              void* d_out, int out_size, void* d_ws, size_t ws_size,
                              hipStream_t stream) {
    const float* x      = (const float*)d_in[0];
    const float* weight = (const float*)d_in[1];
    const float* bias   = (const float*)d_in[2];
    float* out = (float*)d_out;

    static bool init = false;
    if (!init) {
        (void)hipFuncSetAttribute((const void*)sge_kernel,
                                  hipFuncAttributeMaxDynamicSharedMemorySize,
                                  LDS_TOTAL);
        init = true;
    }
    sge_kernel<<<dim3(512), dim3(512), LDS_TOTAL, stream>>>(x, weight, bias, out);
}